// Round 9
// baseline (479.075 us; speedup 1.0000x reference)
//
#include <hip/hip_runtime.h>
#include <cstdint>
#include <cstddef>

typedef _Float16 f16;
typedef _Float16 half8 __attribute__((ext_vector_type(8)));
typedef _Float16 half4 __attribute__((ext_vector_type(4)));
typedef float f32x4 __attribute__((ext_vector_type(4)));

constexpr int CDIM = 192, HW = 3136, NBAT = 4, TSTEPS = 16;
constexpr int ROWS = 16;
constexpr int CPB  = HW / ROWS;      // 196 chunks per batch
constexpr int NBLK = NBAT * CPB;     // 784 blocks

// ---------------- weight packing: W2[nsl12][gate3][kt12][lane64][8] f16 ----------------
// B-fragment order for 16x16x32: lane=(kgrp<<4)|(n&15), slot i -> k = kt*32+kgrp*8+i
__global__ void pack_w(const float* __restrict__ wz, const float* __restrict__ wr,
                       const float* __restrict__ wh, f16* __restrict__ W2) {
    int idx = blockIdx.x * 256 + threadIdx.x;     // 864*256 = 221184 exactly
    if (idx >= 12 * 3 * 12 * 512) return;
    int i = idx & 7, lane = (idx >> 3) & 63, f = idx >> 9;
    int kt = f % 12, gate = (f / 12) % 3, nsl = f / 36;
    int n = nsl * 16 + (lane & 15);               // output channel
    int k = kt * 32 + ((lane >> 4) * 8) + i;      // input channel, K=384 = [x|h]
    const float* W = (gate == 0) ? wz : (gate == 1) ? wr : wh;
    W2[idx] = (f16)W[n * 384 + k];
}

// ---------------- single-launch kernel: all 16 steps, ALL weights in registers ----------------
// Block = 16 rows x full N=192; 12 waves, wave wv owns cols [16wv,16wv+16).
// Per lane: 36 half8 = 144 VGPR of weights (z,r,h; full K=384), held across the t-loop.
// h lives in LDS; x staged per step; U/xproj eliminated. HBM = video(154) + dout(308), once.
// LDS tiles [16][192] f16, row stride 384B, XOR swizzle ((row&7)<<4) on in-row byte.
__global__ __launch_bounds__(768, 3) void gru_all(
    const float* __restrict__ video, const f16* __restrict__ W2,
    const float* __restrict__ bz, const float* __restrict__ br,
    const float* __restrict__ bh, float* __restrict__ dout) {
    __shared__ __align__(16) char AX[6144], AH[6144], RH[6144];
    const int tid = threadIdx.x, wv = tid >> 6, lane = tid & 63;
    const int l15 = lane & 15, lg = lane >> 4;
    const int ch = blockIdx.x, bb = ch / CPB, hw0 = (ch % CPB) * ROWS;
    const int slot = (l15 & 7) << 4;
    const int col = wv * 16 + l15;

    // ---- load this wave's weights into registers (read once per block) ----
    half8 wz_[12], wr_[12], wh_[12];
    {
        const f16* wb = W2 + (size_t)wv * 36 * 512 + lane * 8;
#pragma unroll
        for (int kt = 0; kt < 12; ++kt) {
            wz_[kt] = *(const half8*)(wb + (size_t)kt * 512);
            wr_[kt] = *(const half8*)(wb + (size_t)(12 + kt) * 512);
            wh_[kt] = *(const half8*)(wb + (size_t)(24 + kt) * 512);
        }
    }
    const float vbz = bz[col], vbr = br[col], vbh = bh[col];

    // staging coords: thread = (hw 0..15) x (c-group 0..47 of 4 channels)
    const int shw = tid & 15, scg = tid >> 4;
    const int sbyte = shw * 384 + ((scg * 8) ^ ((shw & 7) << 4));
    const float* vp = video + (size_t)bb * TSTEPS * CDIM * HW + (size_t)scg * 4 * HW + hw0 + shw;
    float*       op = dout  + (size_t)bb * TSTEPS * CDIM * HW + (size_t)scg * 4 * HW + hw0 + shw;

    // h0 = 0 (zeros swizzle-invariant); stage x for t=0
    {
        *(uint64_t*)(AH + tid * 8) = 0ull;
        half4 hv;
        hv[0] = (f16)__builtin_nontemporal_load(vp);
        hv[1] = (f16)__builtin_nontemporal_load(vp + HW);
        hv[2] = (f16)__builtin_nontemporal_load(vp + 2 * HW);
        hv[3] = (f16)__builtin_nontemporal_load(vp + 3 * HW);
        *(half4*)(AX + sbyte) = hv;
    }
    __syncthreads();

#pragma unroll 1
    for (int t = 0; t < TSTEPS; ++t) {
        // T14: issue next-step x loads now; convert+LDS-write after B1
        float p0, p1, p2, p3;
        if (t + 1 < TSTEPS) {
            const float* np = vp + (size_t)(t + 1) * CDIM * HW;
            p0 = __builtin_nontemporal_load(np);
            p1 = __builtin_nontemporal_load(np + HW);
            p2 = __builtin_nontemporal_load(np + 2 * HW);
            p3 = __builtin_nontemporal_load(np + 3 * HW);
        }

        // ---- phase 1: K=384 for z,r + x-half (kt 0..5) of h-gate, fused on shared A-frag ----
        f32x4 az = {vbz, vbz, vbz, vbz};      // bias pre-loaded as MFMA C-in
        f32x4 ar = {vbr, vbr, vbr, vbr};
        f32x4 ac = {vbh, vbh, vbh, vbh};
#pragma unroll
        for (int kt = 0; kt < 12; ++kt) {
            const char* ab = (kt < 6) ? AX : AH;
            half8 a = *(const half8*)(ab + l15 * 384 + ((((kt % 6) * 64) + lg * 16) ^ slot));
            az = __builtin_amdgcn_mfma_f32_16x16x32_f16(a, wz_[kt], az, 0, 0, 0);
            ar = __builtin_amdgcn_mfma_f32_16x16x32_f16(a, wr_[kt], ar, 0, 0, 0);
            if (kt < 6)
                ac = __builtin_amdgcn_mfma_f32_16x16x32_f16(a, wh_[kt], ac, 0, 0, 0);
        }

        // ---- gates: z,(1-z)h kept in regs; r*h -> RH.  C/D map col=lane&15,row=(lane>>4)*4+q ----
        float zg[4], ho[4];
#pragma unroll
        for (int q = 0; q < 4; ++q) {
            int row = lg * 4 + q;
            int cb = (2 * col) ^ ((row & 7) << 4);
            float z = 1.f / (1.f + __expf(-az[q]));
            float r = 1.f / (1.f + __expf(-ar[q]));
            float h = (float)*(const f16*)(AH + row * 384 + cb);
            zg[q] = z; ho[q] = (1.f - z) * h;
            *(f16*)(RH + row * 384 + cb) = (f16)(r * h);
        }
        __syncthreads();   // B1: RH ready; all AX/AH readers of this step done

        // restage AX for t+1 (AX dead after phase 1); overlaps phase 2
        if (t + 1 < TSTEPS) {
            half4 hv = {(f16)p0, (f16)p1, (f16)p2, (f16)p3};
            *(half4*)(AX + sbyte) = hv;
        }

        // ---- phase 2: h-gate tail, A = r*h (kt 6..11) ----
#pragma unroll
        for (int kt = 6; kt < 12; ++kt) {
            half8 a = *(const half8*)(RH + l15 * 384 + ((((kt - 6) * 64) + lg * 16) ^ slot));
            ac = __builtin_amdgcn_mfma_f32_16x16x32_f16(a, wh_[kt], ac, 0, 0, 0);
        }

        // ---- epilogue: h_new = (1-z)h + z*tanh -> AH (no AH re-read: ho cached) ----
#pragma unroll
        for (int q = 0; q < 4; ++q) {
            int row = lg * 4 + q;
            int cb = (2 * col) ^ ((row & 7) << 4);
            float e = __expf(2.f * ac[q]);
            float th = 1.f - 2.f / (e + 1.f);
            *(f16*)(AH + row * 384 + cb) = (f16)(ho[q] + zg[q] * th);
        }
        __syncthreads();   // B2: AH(t) final; AX(t+1) staged

        // ---- dout writeout (nt stores, 64B runs per instruction) ----
        {
            float* ob = op + (size_t)t * CDIM * HW;
            half4 hv = *(const half4*)(AH + sbyte);
            __builtin_nontemporal_store((float)hv[0], ob);
            __builtin_nontemporal_store((float)hv[1], ob + HW);
            __builtin_nontemporal_store((float)hv[2], ob + 2 * HW);
            __builtin_nontemporal_store((float)hv[3], ob + 3 * HW);
        }
    }
}

extern "C" void kernel_launch(void* const* d_in, const int* in_sizes, int n_in,
                              void* d_out, int out_size, void* d_ws, size_t ws_size,
                              hipStream_t stream) {
    const float* video = (const float*)d_in[0];
    const float* wz = (const float*)d_in[1];
    const float* bz = (const float*)d_in[2];
    const float* wr = (const float*)d_in[3];
    const float* br = (const float*)d_in[4];
    const float* wh = (const float*)d_in[5];
    const float* bh = (const float*)d_in[6];
    f16* W2 = (f16*)d_ws;
    float* dout = (float*)d_out;

    pack_w<<<864, 256, 0, stream>>>(wz, wr, wh, W2);
    gru_all<<<NBLK, 768, 0, stream>>>(video, W2, bz, br, bh, dout);
}

// Round 10
// 238.036 us; speedup vs baseline: 2.0126x; 2.0126x over previous
//
#include <hip/hip_runtime.h>
#include <cstdint>
#include <cstddef>

typedef _Float16 f16;
typedef _Float16 half8 __attribute__((ext_vector_type(8)));
typedef _Float16 half4 __attribute__((ext_vector_type(4)));
typedef float f32x4 __attribute__((ext_vector_type(4)));
typedef unsigned int u32;
typedef u32 u32x4 __attribute__((ext_vector_type(4)));

constexpr int CDIM = 192, HW = 3136, NBAT = 4, TSTEPS = 16;
constexpr int MTOT = NBAT * HW;     // 12544
constexpr int NSUB = MTOT / 16;     // 784 16-row subtiles
constexpr int NCHUNK = MTOT / 32;   // 392 recur blocks (2 subtiles each)

// ---- primary-path workspace layout (bytes) ----
constexpr size_t OFF_WX = 0;                      // [kt6][nt36][lane64][8] f16
constexpr size_t SZ_WX  = (size_t)6*36*64*8*2;    // 221184
constexpr size_t OFF_WHB = OFF_WX + SZ_WX;        // [nsl12][gate3][kt6][lane64][8] f16
constexpr size_t SZ_WHB  = (size_t)12*3*6*64*8*2; // 221184
constexpr size_t OFF_U  = OFF_WHB + SZ_WHB;       // [t16][sub784][nsl12][gate3][lane64][4] f16
constexpr size_t SZ_U   = (size_t)16*NSUB*12*3*64*4*2; // 231,211,008
constexpr size_t NEED   = OFF_U + SZ_U;

// ---- fallback (R5) workspace layout ----
constexpr size_t FB_WZR = 0;
constexpr size_t FB_SZ_WZR = (size_t)384*384*2;
constexpr size_t FB_WH  = FB_WZR + FB_SZ_WZR;

// =================== primary path ===================

// pack: WX in B-fragment order (k = x-half), WHB per-(nsl,gate,kt) fragments (k = h-half)
__global__ void pack_w(const float* __restrict__ wz, const float* __restrict__ wr,
                       const float* __restrict__ wh, char* __restrict__ ws) {
    int idx = blockIdx.x * 256 + threadIdx.x;   // 864*256 = 221184 exactly
    if (idx >= 221184) return;
    f16* dst;
    int lane, i, k, c, gate;
    if (idx < 110592) {
        i = idx & 7; lane = (idx >> 3) & 63;
        int ktnt = idx >> 9, kt = ktnt / 36, nt = ktnt % 36;
        int n576 = nt * 16 + (lane & 15);
        gate = n576 / 192; c = n576 % 192;
        k = kt * 32 + (lane >> 4) * 8 + i;                 // x half
        dst = (f16*)(ws + OFF_WX) + idx;
    } else {
        int j = idx - 110592;
        i = j & 7; lane = (j >> 3) & 63;
        int a = j >> 9, kt = a % 6, b = a / 6;
        gate = b % 3; int nsl = b / 3;
        c = nsl * 16 + (lane & 15);
        k = 192 + kt * 32 + (lane >> 4) * 8 + i;           // h half
        dst = (f16*)(ws + OFF_WHB) + j;
    }
    const float* W = (gate == 0) ? wz : (gate == 1) ? wr : wh;
    *dst = (f16)W[c * 384 + k];
}

// xproj: U[t][sub][nsl][gate][lane][4] = x·Wx + bias in recur fragment order.
// Block = 2 t-planes x 64 hw rows; 8 waves: mg=w>>2 -> plane, nw=w&3 -> 144 cols.
__global__ __launch_bounds__(512, 2) void xproj(
    const float* __restrict__ video, char* __restrict__ ws,
    const float* __restrict__ bz, const float* __restrict__ br,
    const float* __restrict__ bh) {
    __shared__ __align__(16) char AX[2][24576];  // [64][192] f16, swizzled
    const f16* WX = (const f16*)(ws + OFF_WX);
    f16* U = (f16*)(ws + OFF_U);
    const int tid = threadIdx.x, w = tid >> 6, lane = tid & 63;
    const int l15 = lane & 15, lg = lane >> 4;
    const int mt = blockIdx.x;               // 0..195
    const int bb = mt / 49, hw0 = (mt % 49) * 64;
    const int t0 = blockIdx.y * 2;
    const int mg = w >> 2, nw = w & 3;
    const int swsh = (lane & 7) << 4;
    const int slot = (l15 & 7) << 4;

    // stage both planes (thread: hw=lane, 24 channels via wave id)
#pragma unroll
    for (int p = 0; p < 2; ++p) {
        const float* vs = video + ((size_t)(bb * TSTEPS + t0 + p) * CDIM) * HW + hw0 + lane;
#pragma unroll
        for (int g = 0; g < 3; ++g) {
            half8 hv;
#pragma unroll
            for (int j = 0; j < 8; ++j)
                hv[j] = (f16)__builtin_nontemporal_load(vs + (size_t)(w * 24 + g * 8 + j) * HW);
            *(half8*)(AX[p] + lane * 384 + ((w * 48 + g * 16) ^ swsh)) = hv;
        }
    }
    float vb[9];
#pragma unroll
    for (int r = 0; r < 9; ++r) {
        int n576 = nw * 144 + r * 16 + l15;
        int gate = n576 / 192, c = n576 % 192;
        vb[r] = (gate == 0 ? bz : (gate == 1 ? br : bh))[c];
    }
    __syncthreads();

    f32x4 acc[4][9];
#pragma unroll
    for (int i = 0; i < 4; ++i)
#pragma unroll
        for (int r = 0; r < 9; ++r)
#pragma unroll
            for (int q = 0; q < 4; ++q) acc[i][r][q] = vb[r];   // bias as C-in

#pragma unroll
    for (int kt = 0; kt < 6; ++kt) {
        half8 a[4];
#pragma unroll
        for (int i = 0; i < 4; ++i)
            a[i] = *(const half8*)(AX[mg] + (i * 16 + l15) * 384 + ((kt * 64 + lg * 16) ^ slot));
#pragma unroll
        for (int r = 0; r < 9; ++r) {
            half8 bf = *(const half8*)(WX + ((size_t)(kt * 36 + nw * 9 + r) * 64 + lane) * 8);
#pragma unroll
            for (int i = 0; i < 4; ++i)
                acc[i][r] = __builtin_amdgcn_mfma_f32_16x16x32_f16(a[i], bf, acc[i][r], 0, 0, 0);
        }
    }
    // store U: per (r,i) one dense half4/lane (64x8B = 512B covered lines), nontemporal
    const int t = t0 + mg;
#pragma unroll
    for (int r = 0; r < 9; ++r) {
        int nb = nw * 9 + r;                 // n-frag index 0..35
        int gate = nb / 12, nsl = nb % 12;
#pragma unroll
        for (int i = 0; i < 4; ++i) {
            half4 hq;
#pragma unroll
            for (int q = 0; q < 4; ++q) hq[q] = (f16)acc[i][r][q];
            int sub = mt * 4 + i;
            f16* up = U + (((size_t)t * NSUB + sub) * 36 + (size_t)nsl * 3 + gate) * 256
                        + (size_t)lane * 4;
            __builtin_nontemporal_store(hq, (half4*)up);
        }
    }
}

// recur: 392 blocks x 768 threads (12 waves = n-slices of 16 cols).
// Wh (h-half, K=192) in registers (72 VGPR/lane) for all 16 steps; h in LDS;
// U streamed once with dense 8B/lane nt loads, double-buffered across t.
__global__ __launch_bounds__(768, 3) void recur(const char* __restrict__ ws,
                                                float* __restrict__ dout) {
    __shared__ __align__(16) char AH[12288], RH[12288];   // [32][192] f16, swizzled
    const f16* WHB = (const f16*)(ws + OFF_WHB);
    const f16* U = (const f16*)(ws + OFF_U);
    const int tid = threadIdx.x, wv = tid >> 6, lane = tid & 63;  // wv = nsl
    const int l15 = lane & 15, lg = lane >> 4;
    const int ch = blockIdx.x;                 // 0..391
    const int bb = ch / 98, hw0 = (ch % 98) * 32;
    const int slot = (l15 & 7) << 4;

    half8 wz_[6], wr_[6], wh_[6];
    {
        const f16* base = WHB + (size_t)wv * 9216 + lane * 8;
#pragma unroll
        for (int kt = 0; kt < 6; ++kt) {
            wz_[kt] = *(const half8*)(base + (0 * 6 + kt) * 512);
            wr_[kt] = *(const half8*)(base + (1 * 6 + kt) * 512);
            wh_[kt] = *(const half8*)(base + (2 * 6 + kt) * 512);
        }
    }
    {   // h0 = 0
        u32x4 z = {0, 0, 0, 0};
        *(u32x4*)(AH + tid * 16) = z;
    }
    __syncthreads();

    // U base for this block/wave: per (t,sub): +36*256 f16; sub = ch*2+i
    const f16* ub = U + ((size_t)ch * 2 * 36 + (size_t)wv * 3) * 256 + (size_t)lane * 4;
    constexpr size_t UT = (size_t)NSUB * 36 * 256;   // f16 per t
    // prefetch U(t=0)
    half4 uz0 = __builtin_nontemporal_load((const half4*)(ub));
    half4 ur0 = __builtin_nontemporal_load((const half4*)(ub + 256));
    half4 uh0 = __builtin_nontemporal_load((const half4*)(ub + 512));
    half4 uz1 = __builtin_nontemporal_load((const half4*)(ub + 36 * 256));
    half4 ur1 = __builtin_nontemporal_load((const half4*)(ub + 36 * 256 + 256));
    half4 uh1 = __builtin_nontemporal_load((const half4*)(ub + 36 * 256 + 512));

    const int ohw = tid & 31, ocg = tid >> 5;   // writeout: row, col-group (8 ch)
    const int obyte = ohw * 384 + ((ocg * 16) ^ ((ohw & 7) << 4));
    float* obase = dout + (size_t)bb * TSTEPS * CDIM * HW + (size_t)ocg * 8 * HW + hw0 + ohw;

#pragma unroll 1
    for (int t = 0; t < TSTEPS; ++t) {
        // phase 1: z,r recurrent GEMM (A = h from AH, B = regs)
        f32x4 az[2], ar[2];
#pragma unroll
        for (int i = 0; i < 2; ++i)
#pragma unroll
            for (int q = 0; q < 4; ++q) { az[i][q] = 0.f; ar[i][q] = 0.f; }
#pragma unroll
        for (int kt = 0; kt < 6; ++kt) {
            half8 a0 = *(const half8*)(AH + l15 * 384 + ((kt * 64 + lg * 16) ^ slot));
            half8 a1 = *(const half8*)(AH + (16 + l15) * 384 + ((kt * 64 + lg * 16) ^ slot));
            az[0] = __builtin_amdgcn_mfma_f32_16x16x32_f16(a0, wz_[kt], az[0], 0, 0, 0);
            az[1] = __builtin_amdgcn_mfma_f32_16x16x32_f16(a1, wz_[kt], az[1], 0, 0, 0);
            ar[0] = __builtin_amdgcn_mfma_f32_16x16x32_f16(a0, wr_[kt], ar[0], 0, 0, 0);
            ar[1] = __builtin_amdgcn_mfma_f32_16x16x32_f16(a1, wr_[kt], ar[1], 0, 0, 0);
        }
        // gates: z,(1-z)h in regs; r*h -> RH.  C/D map col=lane&15, row=(lane>>4)*4+q
        float zg[2][4], ho[2][4];
#pragma unroll
        for (int i = 0; i < 2; ++i)
#pragma unroll
            for (int q = 0; q < 4; ++q) {
                int row = i * 16 + lg * 4 + q;
                int cb = 2 * (wv * 16 + l15), sw = (row & 7) << 4;
                float uzv = (float)(i ? uz1[q] : uz0[q]);
                float urv = (float)(i ? ur1[q] : ur0[q]);
                float z = 1.f / (1.f + __expf(-(az[i][q] + uzv)));
                float r = 1.f / (1.f + __expf(-(ar[i][q] + urv)));
                float h = (float)*(const f16*)(AH + row * 384 + (cb ^ sw));
                zg[i][q] = z; ho[i][q] = (1.f - z) * h;
                *(f16*)(RH + row * 384 + (cb ^ sw)) = (f16)(r * h);
            }
        __syncthreads();   // B1: RH complete

        // prefetch U(t+1) — overlaps phase 2
        half4 nz0 = uz0, nr0 = ur0, nh0 = uh0, nz1 = uz1, nr1 = ur1, nh1 = uh1;
        if (t + 1 < TSTEPS) {
            const f16* un = ub + (size_t)(t + 1) * UT;
            nz0 = __builtin_nontemporal_load((const half4*)(un));
            nr0 = __builtin_nontemporal_load((const half4*)(un + 256));
            nh0 = __builtin_nontemporal_load((const half4*)(un + 512));
            nz1 = __builtin_nontemporal_load((const half4*)(un + 36 * 256));
            nr1 = __builtin_nontemporal_load((const half4*)(un + 36 * 256 + 256));
            nh1 = __builtin_nontemporal_load((const half4*)(un + 36 * 256 + 512));
        }

        // phase 2: h-candidate recurrent GEMM (A = r*h)
        f32x4 ah[2];
#pragma unroll
        for (int i = 0; i < 2; ++i)
#pragma unroll
            for (int q = 0; q < 4; ++q) ah[i][q] = 0.f;
#pragma unroll
        for (int kt = 0; kt < 6; ++kt) {
            half8 a0 = *(const half8*)(RH + l15 * 384 + ((kt * 64 + lg * 16) ^ slot));
            half8 a1 = *(const half8*)(RH + (16 + l15) * 384 + ((kt * 64 + lg * 16) ^ slot));
            ah[0] = __builtin_amdgcn_mfma_f32_16x16x32_f16(a0, wh_[kt], ah[0], 0, 0, 0);
            ah[1] = __builtin_amdgcn_mfma_f32_16x16x32_f16(a1, wh_[kt], ah[1], 0, 0, 0);
        }
        // epilogue: h_new = (1-z)h + z*tanh -> AH (no AH re-read)
#pragma unroll
        for (int i = 0; i < 2; ++i)
#pragma unroll
            for (int q = 0; q < 4; ++q) {
                int row = i * 16 + lg * 4 + q;
                int cb = 2 * (wv * 16 + l15), sw = (row & 7) << 4;
                float uhv = (float)(i ? uh1[q] : uh0[q]);
                float e = __expf(2.f * (ah[i][q] + uhv));
                float th = 1.f - 2.f / (e + 1.f);
                *(f16*)(AH + row * 384 + (cb ^ sw)) = (f16)(ho[i][q] + zg[i][q] * th);
            }
        __syncthreads();   // B2: AH complete

        // writeout (reads AH; next AH writes fenced by next B1)
        {
            half8 hv = *(const half8*)(AH + obyte);
            float* ob = obase + (size_t)t * CDIM * HW;
#pragma unroll
            for (int j = 0; j < 8; ++j)
                __builtin_nontemporal_store((float)hv[j], ob + (size_t)j * HW);
        }
        uz0 = nz0; ur0 = nr0; uh0 = nh0; uz1 = nz1; ur1 = nr1; uh1 = nh1;
    }
}

// =================== fallback path (R5, needs 442 KB ws) ===================

__global__ void pack5(const float* __restrict__ wz, const float* __restrict__ wr,
                      const float* __restrict__ wh, char* __restrict__ ws) {
    int idx = blockIdx.x * 256 + threadIdx.x;
    const int ZRT = 384 * 384;
    int n, k, NT;
    float w;
    f16* dst;
    if (idx < ZRT) {
        n = idx / 384; k = idx - n * 384;
        w = (n < 192) ? wz[n * 384 + k] : wr[(n - 192) * 384 + k];
        dst = (f16*)(ws + FB_WZR); NT = 24;
    } else {
        int j = idx - ZRT;
        if (j >= 192 * 384) return;
        n = j / 384; k = j - n * 384;
        w = wh[n * 384 + k];
        dst = (f16*)(ws + FB_WH); NT = 12;
    }
    int kt = k >> 5, g = (k >> 3) & 3, i = k & 7, nt = n >> 4;
    int lane = (g << 4) | (n & 15);
    dst[((size_t)(kt * NT + nt) * 64 + lane) * 8 + i] = (f16)w;
}

__global__ __launch_bounds__(256, 2) void gru_fb(
    const float* __restrict__ video,
    const f16* __restrict__ wZR, const f16* __restrict__ wH,
    const float* __restrict__ bz, const float* __restrict__ br,
    const float* __restrict__ bh, float* __restrict__ dout) {
    __shared__ __align__(16) char smem[73728];
    char* AX = smem;
    char* AH = smem + 24576;
    char* RH = smem + 49152;
    const int tid = threadIdx.x, w = tid >> 6, lane = tid & 63;
    const int l15 = lane & 15, lg = lane >> 4;
    const int mt = blockIdx.x, bb = mt / 49, hw0 = (mt % 49) * 64;
    const int slot = (l15 & 7) << 4;
    const int swsh = (lane & 7) << 4;
    const float* vbase = video + (size_t)bb * TSTEPS * CDIM * HW + hw0 + lane;
    float* obase = dout + (size_t)bb * TSTEPS * CDIM * HW + hw0 + lane;
    float vbz[3], vbr[3], vbh[3];
#pragma unroll
    for (int r = 0; r < 3; ++r) {
        int c = w * 48 + r * 16 + l15;
        vbz[r] = bz[c]; vbr[r] = br[c]; vbh[r] = bh[c];
    }
    {
        half8 zz = {};
#pragma unroll
        for (int i = 0; i < 6; ++i) *(half8*)(AH + tid * 96 + i * 16) = zz;
#pragma unroll
        for (int g = 0; g < 6; ++g) {
            half8 hv;
#pragma unroll
            for (int j = 0; j < 8; ++j)
                hv[j] = (f16)__builtin_nontemporal_load(vbase + (size_t)(w * 48 + g * 8 + j) * HW);
            *(half8*)(AX + lane * 384 + ((w * 96 + g * 16) ^ swsh)) = hv;
        }
    }
    __syncthreads();
#pragma unroll 1
    for (int t = 0; t < TSTEPS; ++t) {
        f32x4 az[4][3], ar[4][3];
#pragma unroll
        for (int i = 0; i < 4; ++i)
#pragma unroll
            for (int r = 0; r < 3; ++r)
#pragma unroll
                for (int q = 0; q < 4; ++q) { az[i][r][q] = 0.f; ar[i][r][q] = 0.f; }
#pragma unroll
        for (int kt = 0; kt < 12; ++kt) {
            const char* ab = (kt < 6) ? AX : AH;
            int kb = (kt % 6) * 64 + lg * 16;
            half8 a[4];
#pragma unroll
            for (int i = 0; i < 4; ++i)
                a[i] = *(const half8*)(ab + (i * 16 + l15) * 384 + (kb ^ slot));
#pragma unroll
            for (int r = 0; r < 3; ++r) {
                half8 bzf = *(const half8*)(wZR + ((size_t)(kt * 24 + w * 3 + r) * 64 + lane) * 8);
                half8 brf = *(const half8*)(wZR + ((size_t)(kt * 24 + 12 + w * 3 + r) * 64 + lane) * 8);
#pragma unroll
                for (int i = 0; i < 4; ++i)
                    az[i][r] = __builtin_amdgcn_mfma_f32_16x16x32_f16(a[i], bzf, az[i][r], 0, 0, 0);
#pragma unroll
                for (int i = 0; i < 4; ++i)
                    ar[i][r] = __builtin_amdgcn_mfma_f32_16x16x32_f16(a[i], brf, ar[i][r], 0, 0, 0);
            }
        }
        float xn[6][8];
        if (t + 1 < TSTEPS) {
            const float* vs = vbase + (size_t)(t + 1) * CDIM * HW;
#pragma unroll
            for (int g = 0; g < 6; ++g)
#pragma unroll
                for (int j = 0; j < 8; ++j)
                    xn[g][j] = __builtin_nontemporal_load(vs + (size_t)(w * 48 + g * 8 + j) * HW);
        }
#pragma unroll
        for (int i = 0; i < 4; ++i)
#pragma unroll
            for (int r = 0; r < 3; ++r)
#pragma unroll
                for (int q = 0; q < 4; ++q) {
                    int row = i * 16 + lg * 4 + q;
                    int cb = 2 * (w * 48 + r * 16 + l15), sw = (row & 7) << 4;
                    float rg = 1.f / (1.f + __expf(-(ar[i][r][q] + vbr[r])));
                    float hv = (float)*(const f16*)(AH + row * 384 + (cb ^ sw));
                    *(f16*)(RH + row * 384 + (cb ^ sw)) = (f16)(rg * hv);
                }
        __syncthreads();
        f32x4 ac[4][3];
#pragma unroll
        for (int i = 0; i < 4; ++i)
#pragma unroll
            for (int r = 0; r < 3; ++r)
#pragma unroll
                for (int q = 0; q < 4; ++q) ac[i][r][q] = 0.f;
#pragma unroll
        for (int kt = 0; kt < 12; ++kt) {
            const char* ab = (kt < 6) ? AX : RH;
            int kb = (kt % 6) * 64 + lg * 16;
            half8 a[4];
#pragma unroll
            for (int i = 0; i < 4; ++i)
                a[i] = *(const half8*)(ab + (i * 16 + l15) * 384 + (kb ^ slot));
#pragma unroll
            for (int r = 0; r < 3; ++r) {
                half8 bf = *(const half8*)(wH + ((size_t)(kt * 12 + w * 3 + r) * 64 + lane) * 8);
#pragma unroll
                for (int i = 0; i < 4; ++i)
                    ac[i][r] = __builtin_amdgcn_mfma_f32_16x16x32_f16(a[i], bf, ac[i][r], 0, 0, 0);
            }
        }
#pragma unroll
        for (int i = 0; i < 4; ++i)
#pragma unroll
            for (int r = 0; r < 3; ++r)
#pragma unroll
                for (int q = 0; q < 4; ++q) {
                    int row = i * 16 + lg * 4 + q;
                    int cb = 2 * (w * 48 + r * 16 + l15), sw = (row & 7) << 4;
                    float zgv = 1.f / (1.f + __expf(-(az[i][r][q] + vbz[r])));
                    float e = __expf(2.f * (ac[i][r][q] + vbh[r]));
                    float th = 1.f - 2.f / (e + 1.f);
                    float hold = (float)*(const f16*)(AH + row * 384 + (cb ^ sw));
                    *(f16*)(AH + row * 384 + (cb ^ sw)) = (f16)((1.f - zgv) * hold + zgv * th);
                }
        __syncthreads();
        {
            float* ob = obase + (size_t)t * CDIM * HW;
#pragma unroll
            for (int g = 0; g < 6; ++g) {
                half8 hv = *(const half8*)(AH + lane * 384 + ((w * 96 + g * 16) ^ swsh));
#pragma unroll
                for (int j = 0; j < 8; ++j)
                    __builtin_nontemporal_store((float)hv[j], ob + (size_t)(w * 48 + g * 8 + j) * HW);
            }
            if (t + 1 < TSTEPS) {
#pragma unroll
                for (int g = 0; g < 6; ++g) {
                    half8 o;
#pragma unroll
                    for (int j = 0; j < 8; ++j) o[j] = (f16)xn[g][j];
                    *(half8*)(AX + lane * 384 + ((w * 96 + g * 16) ^ swsh)) = o;
                }
            }
        }
        __syncthreads();
    }
}

extern "C" void kernel_launch(void* const* d_in, const int* in_sizes, int n_in,
                              void* d_out, int out_size, void* d_ws, size_t ws_size,
                              hipStream_t stream) {
    const float* video = (const float*)d_in[0];
    const float* wz = (const float*)d_in[1];
    const float* bz = (const float*)d_in[2];
    const float* wr = (const float*)d_in[3];
    const float* br = (const float*)d_in[4];
    const float* wh = (const float*)d_in[5];
    const float* bh = (const float*)d_in[6];
    char* ws = (char*)d_ws;
    float* dout = (float*)d_out;

    if (ws_size >= NEED) {
        pack_w<<<864, 256, 0, stream>>>(wz, wr, wh, ws);
        xproj<<<dim3(196, 8), 512, 0, stream>>>(video, ws, bz, br, bh);
        recur<<<NCHUNK, 768, 0, stream>>>(ws, dout);
    } else {
        pack5<<<864, 256, 0, stream>>>(wz, wr, wh, ws);
        gru_fb<<<196, 256, 0, stream>>>(video, (const f16*)(ws + FB_WZR),
                                        (const f16*)(ws + FB_WH), bz, br, bh, dout);
    }
}